// Round 16
// baseline (98.039 us; speedup 1.0000x reference)
//
#include <hip/hip_runtime.h>
#include <float.h>

#define P_TOTAL 8192
#define F_TOTAL 2048
#define TPB     256                      // 4 independent waves (no barriers)

// Correctly-rounded f32 division via shared refined reciprocal (Markstein).
// R8-verified bit-exact on HW.
__device__ __forceinline__ float refine_rcp(float D) {
#pragma clang fp contract(off)
    float r0 = __builtin_amdgcn_rcpf(D);
    float e1 = __builtin_fmaf(-D, r0, 1.0f);
    return __builtin_fmaf(e1, r0, r0);
}
__device__ __forceinline__ float div_rn(float num, float D, float r) {
#pragma clang fp contract(off)
    float q0 = num * r;
    float e  = __builtin_fmaf(-D, q0, num);
    return __builtin_fmaf(e, r, q0);
}

// Scalar region-select, bit-exact vs numpy (proven R2..R15).
__device__ __forceinline__ void region_select(
    float d1, float d2, float d3, float d4, float d5, float d6,
    float va, float vb, float vc, float d43, float d56,
    float g1, float g2, float g3, float g4,
    float& bu, float& bv, float& bw)
{
#pragma clang fp contract(off)
    float G1 = fmaxf(g1, 1e-12f);
    float G2 = fmaxf(g2, 1e-12f);
    float G3 = fmaxf(g3, 1e-12f);
    float G4 = fmaxf(g4, 1e-12f);

    bool cA  = (d1 <= 0.f) & (d2 <= 0.f);
    bool cB  = (d3 >= 0.f) & (d4 <= d3);
    bool cAB = (vc <= 0.f) & (d1 >= 0.f) & (d3 <= 0.f);
    bool cC  = (d6 >= 0.f) & (d5 <= d6);
    bool cAC = (vb <= 0.f) & (d2 >= 0.f) & (d6 <= 0.f);
    bool cBC = (va <= 0.f) & (d43 >= 0.f) & (d56 >= 0.f);

    float nv = cA ? 0.f : cB ? 1.f : cAB ? d1 : cC ? 0.f
             : cAC ? 0.f : cBC ? d43 : vb;
    float nw = cA ? 0.f : cB ? 0.f : cAB ? 0.f : cC ? 1.f
             : cAC ? d2 : cBC ? d43 : vc;
    float D  = cA ? 1.f : cB ? 1.f : cAB ? G1 : cC ? 1.f
             : cAC ? G2 : cBC ? G3 : G4;
    bool fBC = cBC && !(cA || cB || cAB || cC || cAC);

    float r   = refine_rcp(D);
    float qv  = div_rn(nv, D, r);
    float bww = div_rn(nw, D, r);
    float bvv = fBC ? (1.0f - qv) : qv;
    bv = bvv; bw = bww;
    bu = (1.0f - bvv) - bww;
}

// Exact point-vs-tri, R8's verbatim op order (bit-exact vs numpy).
__device__ __forceinline__ float eval_exact(
    float px, float py, float pz, float4 q0, float4 q1, float4 q2)
{
#pragma clang fp contract(off)
    float ax = q0.x, ay = q0.y, az = q0.z;
    float bx = q0.w, by = q1.x, bz = q1.y;
    float cx = q1.z, cy = q1.w, cz = q2.x;

    float abx = bx - ax, aby = by - ay, abz = bz - az;
    float acx = cx - ax, acy = cy - ay, acz = cz - az;
    float apx = px - ax, apy = py - ay, apz = pz - az;
    float d1 = (abx * apx + aby * apy) + abz * apz;
    float d2 = (acx * apx + acy * apy) + acz * apz;
    float bpx = px - bx, bpy = py - by, bpz = pz - bz;
    float d3 = (abx * bpx + aby * bpy) + abz * bpz;
    float d4 = (acx * bpx + acy * bpy) + acz * bpz;
    float cpx = px - cx, cpy = py - cy, cpz = pz - cz;
    float d5 = (abx * cpx + aby * cpy) + abz * cpz;
    float d6 = (acx * cpx + acy * cpy) + acz * cpz;

    float vc = d1 * d4 - d3 * d2;
    float vb = d5 * d2 - d1 * d6;
    float va = d3 * d6 - d5 * d4;
    float d43 = d4 - d3, d56 = d5 - d6;
    float g1 = d1 - d3, g2 = d2 - d6, g3 = d43 + d56, g4 = (va + vb) + vc;

    float bu, bv, bw;
    region_select(d1, d2, d3, d4, d5, d6, va, vb, vc, d43, d56,
                  g1, g2, g3, g4, bu, bv, bw);

    float cpx2 = (ax * bu + bx * bv) + cx * bw;
    float cpy2 = (ay * bu + by * bv) + cy * bw;
    float cpz2 = (az * bu + bz * bv) + cz * bw;
    float dx = px - cpx2, dy = py - cpy2, dz = pz - cpz2;
    return (dx * dx + dy * dy) + dz * dz;
}

// Prep: per-tri plane {n-hat, n-hat.a}, packed verts, A-vertex array.
// |n-hat| err ~2e-7 rel, covered by the 2% prune margin.
__global__ __launch_bounds__(256) void msdf_prep(
    const float* __restrict__ verts, const int* __restrict__ faces,
    float4* __restrict__ pre_n, float4* __restrict__ pre_v,
    float4* __restrict__ pre_a)
{
    int t = blockIdx.x * 256 + threadIdx.x;
    int i0 = faces[3 * t + 0], i1 = faces[3 * t + 1], i2 = faces[3 * t + 2];
    float ax = verts[3 * i0], ay = verts[3 * i0 + 1], az = verts[3 * i0 + 2];
    float bx = verts[3 * i1], by = verts[3 * i1 + 1], bz = verts[3 * i1 + 2];
    float cx = verts[3 * i2], cy = verts[3 * i2 + 1], cz = verts[3 * i2 + 2];
    float e1x = bx - ax, e1y = by - ay, e1z = bz - az;
    float e2x = cx - ax, e2y = cy - ay, e2z = cz - az;
    float nx = e1y * e2z - e1z * e2y;
    float ny = e1z * e2x - e1x * e2z;
    float nz = e1x * e2y - e1y * e2x;
    float nn = (nx * nx + ny * ny) + nz * nz;
    float inv = (nn > 1e-30f) ? (1.0f / sqrtf(nn)) : 0.0f;  // degen -> lb=0
    nx *= inv; ny *= inv; nz *= inv;
    pre_n[t] = make_float4(nx, ny, nz, (nx * ax + ny * ay) + nz * az);
    pre_v[3 * t + 0] = make_float4(ax, ay, az, bx);
    pre_v[3 * t + 1] = make_float4(by, bz, cx, cy);
    pre_v[3 * t + 2] = make_float4(cz, 0.f, 0.f, 0.f);
    pre_a[t] = make_float4(ax, ay, az, 0.f);
}

// One full-width survivor-eval body (n_ev = min(pend,64); dup-head lanes are
// idempotent under the packed min).
#define FLUSH_BODY() do {                                                 \
    int n_ev = pend < 64 ? pend : 64;                                     \
    int j = (lane < n_ev) ? lane : 0;                                     \
    int t = slist[w][(h + j) & 1023];                                     \
    float4 q0 = pre_v[3 * t + 0];                                         \
    float4 q1 = pre_v[3 * t + 1];                                         \
    float4 q2 = pre_v[3 * t + 2];                                         \
    float d2v = eval_exact(px, py, pz, q0, q1, q2);                       \
    unsigned int bits = __float_as_uint(d2v);                             \
    if (bits < best_bits) { best_bits = bits; best_idx = t; }             \
    float ubc = d2v;                                                      \
    for (int off = 32; off; off >>= 1)                                    \
        ubc = fminf(ubc, __shfl_xor(ubc, off, 64));                       \
    ub = fminf(ub, ubc);                                                  \
    h += n_ev; pend -= n_ev;                                              \
} while (0)

// Phase-1 step for 64 tris at t = step*64+lane: plane lb vs ubm, ballot-
// compacted push into the per-wave FIFO ring.
#define PUSH_STEP(step) do {                                              \
    int t = (step) * 64 + lane;                                           \
    float4 n = pre_n[t];                                                  \
    float lv = ((n.x * px + n.y * py) + n.z * pz) - n.w;                  \
    bool pred = (lv * lv <= ubm);                                         \
    unsigned long long m = __ballot(pred);                                \
    if (pred) {                                                           \
        int off = (int)__popcll(m & ((1ull << lane) - 1ull));             \
        slist[w][(h + pend + off) & 1023] = t;                            \
    }                                                                     \
    pend += (int)__popcll(m);                                             \
} while (0)

// Wave-per-point branch-and-bound, barrier-free.
// ub seed: all 2048 A-vertices (valid: actual mesh points). Chunk 0 (tris
// 0..255): phase-1 + FULL drain -> ub becomes exact-eval sharp (R14-measured
// policy; dropping it in R15 regressed). Tris 256..2047: one flat 28-step
// phase-1 with loop-invariant ubm -> all loads/ballots independent, compiler
// can pipeline (R15 was latency-bound at 35% VALUBusy on the per-chunk ub
// serialization). Overflow guard flushes if the 1024-ring nears full (rare;
// correctness-preserving). Stale ubm costs only efficiency: argmin + its
// ulp-tie partners satisfy lb <= min <= ub always -> never pruned; survivors
// get R8's bit-exact eval; packed (bits,idx) min is order-independent ->
// first-match argmin preserved.
__global__ __launch_bounds__(TPB) void msdf_main(
    const float4* __restrict__ pre_n, const float4* __restrict__ pre_v,
    const float4* __restrict__ pre_a,
    const float* __restrict__ points, float* __restrict__ out)
{
    __shared__ int slist[4][1024];       // per-wave survivor ring (16 KB)
    const int tid  = threadIdx.x;
    const int lane = tid & 63;
    const int w    = tid >> 6;
    const int p    = blockIdx.x * 4 + w;

    const float px = points[3 * p], py = points[3 * p + 1], pz = points[3 * p + 2];

    // ub seed: all 2048 A-vertices, two independent min-chains
    float u0 = FLT_MAX, u1 = FLT_MAX;
    #pragma unroll
    for (int s = 0; s < 16; ++s) {
        float4 qa = pre_a[(2 * s) * 64 + lane];
        float4 qb = pre_a[(2 * s + 1) * 64 + lane];
        float dax = px - qa.x, day = py - qa.y, daz = pz - qa.z;
        float dbx = px - qb.x, dby = py - qb.y, dbz = pz - qb.z;
        u0 = fminf(u0, (dax * dax + day * day) + daz * daz);
        u1 = fminf(u1, (dbx * dbx + dby * dby) + dbz * dbz);
    }
    float u = fminf(u0, u1);
    #pragma unroll
    for (int off = 32; off; off >>= 1)
        u = fminf(u, __shfl_xor(u, off, 64));
    float ub = u;

    unsigned int best_bits = 0xFFFFFFFFu;
    int best_idx = 0;
    int pend = 0, h = 0;

    // ---- tris 0..255: phase-1 + full drain (sharpens ub to exact) ----
    {
        float ubm = ub * 1.02f + 1e-18f;
        #pragma unroll
        for (int s = 0; s < 4; ++s) PUSH_STEP(s);
        while (pend > 0) FLUSH_BODY();
    }

    // ---- tris 256..2047: flat pipelined phase-1, fixed ubm ----
    {
        float ubm = ub * 1.02f + 1e-18f;
        for (int s = 4; s < 32; ++s) {
            PUSH_STEP(s);
            if (pend >= 960) {           // ring-overflow guard (rare)
                while (pend >= 64) FLUSH_BODY();
                ubm = ub * 1.02f + 1e-18f;
            }
        }
    }
    while (pend > 0) FLUSH_BODY();       // final drain

    // in-wave packed min: smallest (bits, idx) == first-match argmin
    unsigned long long key =
        ((unsigned long long)best_bits << 32) | (unsigned int)best_idx;
    #pragma unroll
    for (int off = 32; off > 0; off >>= 1) {
        unsigned int hi = (unsigned int)(key >> 32);
        unsigned int lo = (unsigned int)(key & 0xFFFFFFFFu);
        unsigned int ohi = __shfl_down(hi, off, 64);
        unsigned int olo = __shfl_down(lo, off, 64);
        unsigned long long ok = ((unsigned long long)ohi << 32) | olo;
        key = (ok < key) ? ok : key;
    }
    if (lane == 0) {
        out[1 + p]           = __uint_as_float((unsigned int)(key >> 32));
        out[1 + P_TOTAL + p] = (float)(unsigned int)(key & 0xFFFFFFFFu);
    }
}

// Deterministic loss reduction, 1024 threads. out[0] = sum(dist) * 1000/P.
// No atomics (R5: same-address atomicAdds serialize ~19cyc each).
__global__ __launch_bounds__(1024) void msdf_loss(float* __restrict__ out)
{
    __shared__ float wsum[16];
    float s = 0.f;
    #pragma unroll
    for (int k = 0; k < P_TOTAL / 1024; ++k)
        s += out[1 + k * 1024 + threadIdx.x];
    #pragma unroll
    for (int off = 32; off > 0; off >>= 1) s += __shfl_down(s, off, 64);
    int lane = threadIdx.x & 63, w = threadIdx.x >> 6;
    if (lane == 0) wsum[w] = s;
    __syncthreads();
    if (threadIdx.x == 0) {
        float tot = 0.f;
        #pragma unroll
        for (int i = 0; i < 16; ++i) tot += wsum[i];
        out[0] = tot * (1000.0f / (float)P_TOTAL);
    }
}

extern "C" void kernel_launch(void* const* d_in, const int* in_sizes, int n_in,
                              void* d_out, int out_size, void* d_ws, size_t ws_size,
                              hipStream_t stream) {
    const float* verts  = (const float*)d_in[0];
    const int*   faces  = (const int*)d_in[1];
    const float* points = (const float*)d_in[2];
    float* out = (float*)d_out;
    float4* pre_n = (float4*)d_ws;                                      // 32 KB
    float4* pre_v = (float4*)((char*)d_ws + F_TOTAL * 16);              // 96 KB
    float4* pre_a = (float4*)((char*)d_ws + F_TOTAL * 16 * 4);          // 32 KB

    msdf_prep<<<dim3(F_TOTAL / 256), dim3(256), 0, stream>>>(verts, faces, pre_n, pre_v, pre_a);
    msdf_main<<<dim3(P_TOTAL / 4), dim3(TPB), 0, stream>>>(pre_n, pre_v, pre_a, points, out);
    msdf_loss<<<dim3(1), dim3(1024), 0, stream>>>(out);
}

// Round 17
// 87.082 us; speedup vs baseline: 1.1258x; 1.1258x over previous
//
#include <hip/hip_runtime.h>
#include <float.h>

#define P_TOTAL 8192
#define F_TOTAL 2048
#define TPB     256                      // 4 independent waves (no barriers)
#define CHUNK   256
#define NCHUNK  (F_TOTAL / CHUNK)        // 8

// Correctly-rounded f32 division via shared refined reciprocal (Markstein).
// R8-verified bit-exact on HW.
__device__ __forceinline__ float refine_rcp(float D) {
#pragma clang fp contract(off)
    float r0 = __builtin_amdgcn_rcpf(D);
    float e1 = __builtin_fmaf(-D, r0, 1.0f);
    return __builtin_fmaf(e1, r0, r0);
}
__device__ __forceinline__ float div_rn(float num, float D, float r) {
#pragma clang fp contract(off)
    float q0 = num * r;
    float e  = __builtin_fmaf(-D, q0, num);
    return __builtin_fmaf(e, r, q0);
}

// Scalar region-select, bit-exact vs numpy (proven R2..R16).
__device__ __forceinline__ void region_select(
    float d1, float d2, float d3, float d4, float d5, float d6,
    float va, float vb, float vc, float d43, float d56,
    float g1, float g2, float g3, float g4,
    float& bu, float& bv, float& bw)
{
#pragma clang fp contract(off)
    float G1 = fmaxf(g1, 1e-12f);
    float G2 = fmaxf(g2, 1e-12f);
    float G3 = fmaxf(g3, 1e-12f);
    float G4 = fmaxf(g4, 1e-12f);

    bool cA  = (d1 <= 0.f) & (d2 <= 0.f);
    bool cB  = (d3 >= 0.f) & (d4 <= d3);
    bool cAB = (vc <= 0.f) & (d1 >= 0.f) & (d3 <= 0.f);
    bool cC  = (d6 >= 0.f) & (d5 <= d6);
    bool cAC = (vb <= 0.f) & (d2 >= 0.f) & (d6 <= 0.f);
    bool cBC = (va <= 0.f) & (d43 >= 0.f) & (d56 >= 0.f);

    float nv = cA ? 0.f : cB ? 1.f : cAB ? d1 : cC ? 0.f
             : cAC ? 0.f : cBC ? d43 : vb;
    float nw = cA ? 0.f : cB ? 0.f : cAB ? 0.f : cC ? 1.f
             : cAC ? d2 : cBC ? d43 : vc;
    float D  = cA ? 1.f : cB ? 1.f : cAB ? G1 : cC ? 1.f
             : cAC ? G2 : cBC ? G3 : G4;
    bool fBC = cBC && !(cA || cB || cAB || cC || cAC);

    float r   = refine_rcp(D);
    float qv  = div_rn(nv, D, r);
    float bww = div_rn(nw, D, r);
    float bvv = fBC ? (1.0f - qv) : qv;
    bv = bvv; bw = bww;
    bu = (1.0f - bvv) - bww;
}

// Exact point-vs-tri, R8's verbatim op order (bit-exact vs numpy).
__device__ __forceinline__ float eval_exact(
    float px, float py, float pz, float4 q0, float4 q1, float4 q2)
{
#pragma clang fp contract(off)
    float ax = q0.x, ay = q0.y, az = q0.z;
    float bx = q0.w, by = q1.x, bz = q1.y;
    float cx = q1.z, cy = q1.w, cz = q2.x;

    float abx = bx - ax, aby = by - ay, abz = bz - az;
    float acx = cx - ax, acy = cy - ay, acz = cz - az;
    float apx = px - ax, apy = py - ay, apz = pz - az;
    float d1 = (abx * apx + aby * apy) + abz * apz;
    float d2 = (acx * apx + acy * apy) + acz * apz;
    float bpx = px - bx, bpy = py - by, bpz = pz - bz;
    float d3 = (abx * bpx + aby * bpy) + abz * bpz;
    float d4 = (acx * bpx + acy * bpy) + acz * bpz;
    float cpx = px - cx, cpy = py - cy, cpz = pz - cz;
    float d5 = (abx * cpx + aby * cpy) + abz * cpz;
    float d6 = (acx * cpx + acy * cpy) + acz * cpz;

    float vc = d1 * d4 - d3 * d2;
    float vb = d5 * d2 - d1 * d6;
    float va = d3 * d6 - d5 * d4;
    float d43 = d4 - d3, d56 = d5 - d6;
    float g1 = d1 - d3, g2 = d2 - d6, g3 = d43 + d56, g4 = (va + vb) + vc;

    float bu, bv, bw;
    region_select(d1, d2, d3, d4, d5, d6, va, vb, vc, d43, d56,
                  g1, g2, g3, g4, bu, bv, bw);

    float cpx2 = (ax * bu + bx * bv) + cx * bw;
    float cpy2 = (ay * bu + by * bv) + cy * bw;
    float cpz2 = (az * bu + bz * bv) + cz * bw;
    float dx = px - cpx2, dy = py - cpy2, dz = pz - cpz2;
    return (dx * dx + dy * dy) + dz * dz;
}

// Prep: per-tri plane {n-hat, n-hat.a}, packed verts, A-vertex array.
// |n-hat| err ~2e-7 rel, covered by the 2% prune margin.
__global__ __launch_bounds__(256) void msdf_prep(
    const float* __restrict__ verts, const int* __restrict__ faces,
    float4* __restrict__ pre_n, float4* __restrict__ pre_v,
    float4* __restrict__ pre_a)
{
    int t = blockIdx.x * 256 + threadIdx.x;
    int i0 = faces[3 * t + 0], i1 = faces[3 * t + 1], i2 = faces[3 * t + 2];
    float ax = verts[3 * i0], ay = verts[3 * i0 + 1], az = verts[3 * i0 + 2];
    float bx = verts[3 * i1], by = verts[3 * i1 + 1], bz = verts[3 * i1 + 2];
    float cx = verts[3 * i2], cy = verts[3 * i2 + 1], cz = verts[3 * i2 + 2];
    float e1x = bx - ax, e1y = by - ay, e1z = bz - az;
    float e2x = cx - ax, e2y = cy - ay, e2z = cz - az;
    float nx = e1y * e2z - e1z * e2y;
    float ny = e1z * e2x - e1x * e2z;
    float nz = e1x * e2y - e1y * e2x;
    float nn = (nx * nx + ny * ny) + nz * nz;
    float inv = (nn > 1e-30f) ? (1.0f / sqrtf(nn)) : 0.0f;  // degen -> lb=0
    nx *= inv; ny *= inv; nz *= inv;
    pre_n[t] = make_float4(nx, ny, nz, (nx * ax + ny * ay) + nz * az);
    pre_v[3 * t + 0] = make_float4(ax, ay, az, bx);
    pre_v[3 * t + 1] = make_float4(by, bz, cx, cy);
    pre_v[3 * t + 2] = make_float4(cz, 0.f, 0.f, 0.f);
    pre_a[t] = make_float4(ax, ay, az, 0.f);
}

// One eval body over `take` queued survivors (dup-head lanes idempotent).
// NO per-body ub reduce: accumulates per-lane ubloc; caller reduces once per
// chunk (breaks the body->body serialization that kept VALUBusy at 36%).
#define FLUSH_BODY(take) do {                                             \
    int j = (lane < (take)) ? lane : 0;                                   \
    int t = slist[w][(h + j) & 511];                                      \
    float4 q0 = pre_v[3 * t + 0];                                         \
    float4 q1 = pre_v[3 * t + 1];                                         \
    float4 q2 = pre_v[3 * t + 2];                                         \
    float d2v = eval_exact(px, py, pz, q0, q1, q2);                       \
    unsigned int bits = __float_as_uint(d2v);                             \
    if (bits < best_bits) { best_bits = bits; best_idx = t; }             \
    ubloc = fminf(ubloc, d2v);                                            \
    h += (take); pend -= (take);                                          \
} while (0)

// Wave-per-point branch-and-bound, barrier-free (R14 structure, best
// measured: 88.0us total). ub seed: 256 A-vertices (cheap; chunk-0 drain
// sharpens ub to exact right after — R15 showed the 2048-seed is redundant
// latency). Per chunk: plane-lb phase-1 vs ubm, ballot-compacted FIFO push;
// flush full 64-wide bodies on >=64 pending; full drains after chunk 0 and
// at the end. ub updated ONCE per chunk from the batched bodies. Margin 2%
// >> all fp error -> argmin + its ulp-tie partners always survive; survivors
// get R8's bit-exact eval; packed (bits,idx) min is order-independent ->
// first-match argmin preserved.
__global__ __launch_bounds__(TPB) void msdf_main(
    const float4* __restrict__ pre_n, const float4* __restrict__ pre_v,
    const float4* __restrict__ pre_a,
    const float* __restrict__ points, float* __restrict__ out)
{
    __shared__ int slist[4][512];        // per-wave survivor ring (8 KB)
    const int tid  = threadIdx.x;
    const int lane = tid & 63;
    const int w    = tid >> 6;
    const int p    = blockIdx.x * 4 + w;

    const float px = points[3 * p], py = points[3 * p + 1], pz = points[3 * p + 2];

    // ub seed: A-vertices of tris 0..255 (valid: actual mesh points)
    float u = FLT_MAX;
    #pragma unroll
    for (int s = 0; s < 4; ++s) {
        float4 q = pre_a[s * 64 + lane];
        float dx = px - q.x, dy = py - q.y, dz = pz - q.z;
        u = fminf(u, (dx * dx + dy * dy) + dz * dz);
    }
    #pragma unroll
    for (int off = 32; off; off >>= 1)
        u = fminf(u, __shfl_xor(u, off, 64));
    float ub = u;

    unsigned int best_bits = 0xFFFFFFFFu;
    int best_idx = 0;
    int pend = 0, h = 0;

    for (int c = 0; c < NCHUNK; ++c) {
        const float ubm = ub * 1.02f + 1e-18f;
        #pragma unroll
        for (int s = 0; s < 4; ++s) {
            int t = c * CHUNK + s * 64 + lane;
            float4 n = pre_n[t];
            float lv = ((n.x * px + n.y * py) + n.z * pz) - n.w;
            bool pred = (lv * lv <= ubm);
            unsigned long long m = __ballot(pred);
            if (pred) {
                int off = (int)__popcll(m & ((1ull << lane) - 1ull));
                slist[w][(h + pend + off) & 511] = t;
            }
            pend += (int)__popcll(m);
        }

        // batched flush: full bodies (+ masked tail on drain chunks),
        // single ub reduce per chunk
        bool drain = (c == 0) || (c == NCHUNK - 1);
        if (pend >= 64 || (drain && pend > 0)) {
            float ubloc = FLT_MAX;
            while (pend >= 64) FLUSH_BODY(64);
            if (drain && pend > 0) FLUSH_BODY(pend);
            #pragma unroll
            for (int off = 32; off; off >>= 1)
                ubloc = fminf(ubloc, __shfl_xor(ubloc, off, 64));
            ub = fminf(ub, ubloc);
        }
    }

    // in-wave packed min: smallest (bits, idx) == first-match argmin
    unsigned long long key =
        ((unsigned long long)best_bits << 32) | (unsigned int)best_idx;
    #pragma unroll
    for (int off = 32; off > 0; off >>= 1) {
        unsigned int hi = (unsigned int)(key >> 32);
        unsigned int lo = (unsigned int)(key & 0xFFFFFFFFu);
        unsigned int ohi = __shfl_down(hi, off, 64);
        unsigned int olo = __shfl_down(lo, off, 64);
        unsigned long long ok = ((unsigned long long)ohi << 32) | olo;
        key = (ok < key) ? ok : key;
    }
    if (lane == 0) {
        out[1 + p]           = __uint_as_float((unsigned int)(key >> 32));
        out[1 + P_TOTAL + p] = (float)(unsigned int)(key & 0xFFFFFFFFu);
    }
}

// Deterministic single-block loss reduction (R14 config): out[0] =
// sum(dist) * 1000/P. No atomics (R5 lesson).
__global__ __launch_bounds__(256) void msdf_loss(float* __restrict__ out)
{
    __shared__ float wsum[4];
    float s = 0.f;
    for (int k = 0; k < P_TOTAL / 256; ++k)
        s += out[1 + k * 256 + threadIdx.x];
    #pragma unroll
    for (int off = 32; off > 0; off >>= 1) s += __shfl_down(s, off, 64);
    int lane = threadIdx.x & 63, w = threadIdx.x >> 6;
    if (lane == 0) wsum[w] = s;
    __syncthreads();
    if (threadIdx.x == 0) {
        float tot = ((wsum[0] + wsum[1]) + wsum[2]) + wsum[3];
        out[0] = tot * (1000.0f / (float)P_TOTAL);
    }
}

extern "C" void kernel_launch(void* const* d_in, const int* in_sizes, int n_in,
                              void* d_out, int out_size, void* d_ws, size_t ws_size,
                              hipStream_t stream) {
    const float* verts  = (const float*)d_in[0];
    const int*   faces  = (const int*)d_in[1];
    const float* points = (const float*)d_in[2];
    float* out = (float*)d_out;
    float4* pre_n = (float4*)d_ws;                                      // 32 KB
    float4* pre_v = (float4*)((char*)d_ws + F_TOTAL * 16);              // 96 KB
    float4* pre_a = (float4*)((char*)d_ws + F_TOTAL * 16 * 4);          // 32 KB

    msdf_prep<<<dim3(F_TOTAL / 256), dim3(256), 0, stream>>>(verts, faces, pre_n, pre_v, pre_a);
    msdf_main<<<dim3(P_TOTAL / 4), dim3(TPB), 0, stream>>>(pre_n, pre_v, pre_a, points, out);
    msdf_loss<<<dim3(1), dim3(256), 0, stream>>>(out);
}

// Round 18
// 86.466 us; speedup vs baseline: 1.1338x; 1.0071x over previous
//
#include <hip/hip_runtime.h>
#include <float.h>

#define P_TOTAL 8192
#define F_TOTAL 2048
#define TPB     256                  // 4 waves: 2 points x 2 half-scans
#define CHUNK   256
#define HALF_T  (F_TOTAL / 2)        // 1024 tris per wave
#define NCHUNK  (HALF_T / CHUNK)     // 4 chunks per wave

// Correctly-rounded f32 division via shared refined reciprocal (Markstein).
// R8-verified bit-exact on HW.
__device__ __forceinline__ float refine_rcp(float D) {
#pragma clang fp contract(off)
    float r0 = __builtin_amdgcn_rcpf(D);
    float e1 = __builtin_fmaf(-D, r0, 1.0f);
    return __builtin_fmaf(e1, r0, r0);
}
__device__ __forceinline__ float div_rn(float num, float D, float r) {
#pragma clang fp contract(off)
    float q0 = num * r;
    float e  = __builtin_fmaf(-D, q0, num);
    return __builtin_fmaf(e, r, q0);
}

// Scalar region-select, bit-exact vs numpy (proven R2..R17).
__device__ __forceinline__ void region_select(
    float d1, float d2, float d3, float d4, float d5, float d6,
    float va, float vb, float vc, float d43, float d56,
    float g1, float g2, float g3, float g4,
    float& bu, float& bv, float& bw)
{
#pragma clang fp contract(off)
    float G1 = fmaxf(g1, 1e-12f);
    float G2 = fmaxf(g2, 1e-12f);
    float G3 = fmaxf(g3, 1e-12f);
    float G4 = fmaxf(g4, 1e-12f);

    bool cA  = (d1 <= 0.f) & (d2 <= 0.f);
    bool cB  = (d3 >= 0.f) & (d4 <= d3);
    bool cAB = (vc <= 0.f) & (d1 >= 0.f) & (d3 <= 0.f);
    bool cC  = (d6 >= 0.f) & (d5 <= d6);
    bool cAC = (vb <= 0.f) & (d2 >= 0.f) & (d6 <= 0.f);
    bool cBC = (va <= 0.f) & (d43 >= 0.f) & (d56 >= 0.f);

    float nv = cA ? 0.f : cB ? 1.f : cAB ? d1 : cC ? 0.f
             : cAC ? 0.f : cBC ? d43 : vb;
    float nw = cA ? 0.f : cB ? 0.f : cAB ? 0.f : cC ? 1.f
             : cAC ? d2 : cBC ? d43 : vc;
    float D  = cA ? 1.f : cB ? 1.f : cAB ? G1 : cC ? 1.f
             : cAC ? G2 : cBC ? G3 : G4;
    bool fBC = cBC && !(cA || cB || cAB || cC || cAC);

    float r   = refine_rcp(D);
    float qv  = div_rn(nv, D, r);
    float bww = div_rn(nw, D, r);
    float bvv = fBC ? (1.0f - qv) : qv;
    bv = bvv; bw = bww;
    bu = (1.0f - bvv) - bww;
}

// Exact point-vs-tri, R8's verbatim op order (bit-exact vs numpy).
__device__ __forceinline__ float eval_exact(
    float px, float py, float pz, float4 q0, float4 q1, float4 q2)
{
#pragma clang fp contract(off)
    float ax = q0.x, ay = q0.y, az = q0.z;
    float bx = q0.w, by = q1.x, bz = q1.y;
    float cx = q1.z, cy = q1.w, cz = q2.x;

    float abx = bx - ax, aby = by - ay, abz = bz - az;
    float acx = cx - ax, acy = cy - ay, acz = cz - az;
    float apx = px - ax, apy = py - ay, apz = pz - az;
    float d1 = (abx * apx + aby * apy) + abz * apz;
    float d2 = (acx * apx + acy * apy) + acz * apz;
    float bpx = px - bx, bpy = py - by, bpz = pz - bz;
    float d3 = (abx * bpx + aby * bpy) + abz * bpz;
    float d4 = (acx * bpx + acy * bpy) + acz * bpz;
    float cpx = px - cx, cpy = py - cy, cpz = pz - cz;
    float d5 = (abx * cpx + aby * cpy) + abz * cpz;
    float d6 = (acx * cpx + acy * cpy) + acz * cpz;

    float vc = d1 * d4 - d3 * d2;
    float vb = d5 * d2 - d1 * d6;
    float va = d3 * d6 - d5 * d4;
    float d43 = d4 - d3, d56 = d5 - d6;
    float g1 = d1 - d3, g2 = d2 - d6, g3 = d43 + d56, g4 = (va + vb) + vc;

    float bu, bv, bw;
    region_select(d1, d2, d3, d4, d5, d6, va, vb, vc, d43, d56,
                  g1, g2, g3, g4, bu, bv, bw);

    float cpx2 = (ax * bu + bx * bv) + cx * bw;
    float cpy2 = (ay * bu + by * bv) + cy * bw;
    float cpz2 = (az * bu + bz * bv) + cz * bw;
    float dx = px - cpx2, dy = py - cpy2, dz = pz - cpz2;
    return (dx * dx + dy * dy) + dz * dz;
}

// Prep: per-tri plane {n-hat, n-hat.a}, packed verts, A-vertex array.
// |n-hat| err ~2e-7 rel, covered by the 2% prune margin.
__global__ __launch_bounds__(256) void msdf_prep(
    const float* __restrict__ verts, const int* __restrict__ faces,
    float4* __restrict__ pre_n, float4* __restrict__ pre_v,
    float4* __restrict__ pre_a)
{
    int t = blockIdx.x * 256 + threadIdx.x;
    int i0 = faces[3 * t + 0], i1 = faces[3 * t + 1], i2 = faces[3 * t + 2];
    float ax = verts[3 * i0], ay = verts[3 * i0 + 1], az = verts[3 * i0 + 2];
    float bx = verts[3 * i1], by = verts[3 * i1 + 1], bz = verts[3 * i1 + 2];
    float cx = verts[3 * i2], cy = verts[3 * i2 + 1], cz = verts[3 * i2 + 2];
    float e1x = bx - ax, e1y = by - ay, e1z = bz - az;
    float e2x = cx - ax, e2y = cy - ay, e2z = cz - az;
    float nx = e1y * e2z - e1z * e2y;
    float ny = e1z * e2x - e1x * e2z;
    float nz = e1x * e2y - e1y * e2x;
    float nn = (nx * nx + ny * ny) + nz * nz;
    float inv = (nn > 1e-30f) ? (1.0f / sqrtf(nn)) : 0.0f;  // degen -> lb=0
    nx *= inv; ny *= inv; nz *= inv;
    pre_n[t] = make_float4(nx, ny, nz, (nx * ax + ny * ay) + nz * az);
    pre_v[3 * t + 0] = make_float4(ax, ay, az, bx);
    pre_v[3 * t + 1] = make_float4(by, bz, cx, cy);
    pre_v[3 * t + 2] = make_float4(cz, 0.f, 0.f, 0.f);
    pre_a[t] = make_float4(ax, ay, az, 0.f);
}

// One eval body over `take` queued survivors (dup-head lanes idempotent).
// Accumulates per-lane ubloc; caller reduces once per chunk (R17 win).
#define FLUSH_BODY(take) do {                                             \
    int j = (lane < (take)) ? lane : 0;                                   \
    int t = slist[w][(h + j) & 511];                                      \
    float4 q0 = pre_v[3 * t + 0];                                         \
    float4 q1 = pre_v[3 * t + 1];                                         \
    float4 q2 = pre_v[3 * t + 2];                                         \
    float d2v = eval_exact(px, py, pz, q0, q1, q2);                       \
    unsigned int bits = __float_as_uint(d2v);                             \
    if (bits < best_bits) { best_bits = bits; best_idx = t; }             \
    ubloc = fminf(ubloc, d2v);                                            \
    h += (take); pend -= (take);                                          \
} while (0)

// Branch-and-bound, 2 WAVES PER POINT (each wave scans a 1024-tri half ->
// per-wave serial chain halves; R17's main was latency-bound at 36%
// VALUBusy on an 8-chunk sequential walk). Per wave: ub seed from its
// half's first 256 A-verts, per-chunk plane-lb phase-1 vs ubm, ballot-
// compacted FIFO, batched full-width flushes (single ub reduce per chunk),
// drains on first/last chunk. Final cross-wave merge: packed keys via LDS +
// one __syncthreads; min of disjoint-index halves, order-independent ->
// first-match argmin preserved. Survivor evals are R8's bit-exact path;
// 2% margin >> all fp error -> argmin + ulp-tie partners never pruned.
__global__ __launch_bounds__(TPB) void msdf_main(
    const float4* __restrict__ pre_n, const float4* __restrict__ pre_v,
    const float4* __restrict__ pre_a,
    const float* __restrict__ points, float* __restrict__ out)
{
    __shared__ int slist[4][512];                  // per-wave FIFO (8 KB)
    __shared__ unsigned long long keys[4];
    const int tid  = threadIdx.x;
    const int lane = tid & 63;
    const int w    = tid >> 6;
    const int p    = blockIdx.x * 2 + (w >> 1);    // 2 points per block
    const int tb   = (w & 1) * HALF_T;             // this wave's tri base

    const float px = points[3 * p], py = points[3 * p + 1], pz = points[3 * p + 2];

    // ub seed: A-vertices of this half's first 256 tris (actual mesh points)
    float u = FLT_MAX;
    #pragma unroll
    for (int s = 0; s < 4; ++s) {
        float4 q = pre_a[tb + s * 64 + lane];
        float dx = px - q.x, dy = py - q.y, dz = pz - q.z;
        u = fminf(u, (dx * dx + dy * dy) + dz * dz);
    }
    #pragma unroll
    for (int off = 32; off; off >>= 1)
        u = fminf(u, __shfl_xor(u, off, 64));
    float ub = u;

    unsigned int best_bits = 0xFFFFFFFFu;
    int best_idx = 0;
    int pend = 0, h = 0;

    for (int c = 0; c < NCHUNK; ++c) {
        const float ubm = ub * 1.02f + 1e-18f;
        #pragma unroll
        for (int s = 0; s < 4; ++s) {
            int t = tb + c * CHUNK + s * 64 + lane;
            float4 n = pre_n[t];
            float lv = ((n.x * px + n.y * py) + n.z * pz) - n.w;
            bool pred = (lv * lv <= ubm);
            unsigned long long m = __ballot(pred);
            if (pred) {
                int off = (int)__popcll(m & ((1ull << lane) - 1ull));
                slist[w][(h + pend + off) & 511] = t;
            }
            pend += (int)__popcll(m);
        }

        bool drain = (c == 0) || (c == NCHUNK - 1);
        if (pend >= 64 || (drain && pend > 0)) {
            float ubloc = FLT_MAX;
            while (pend >= 64) FLUSH_BODY(64);
            if (drain && pend > 0) FLUSH_BODY(pend);
            #pragma unroll
            for (int off = 32; off; off >>= 1)
                ubloc = fminf(ubloc, __shfl_xor(ubloc, off, 64));
            ub = fminf(ub, ubloc);
        }
    }

    // in-wave packed min, then cross-wave merge of the two halves
    unsigned long long key =
        ((unsigned long long)best_bits << 32) | (unsigned int)best_idx;
    #pragma unroll
    for (int off = 32; off > 0; off >>= 1) {
        unsigned int hi = (unsigned int)(key >> 32);
        unsigned int lo = (unsigned int)(key & 0xFFFFFFFFu);
        unsigned int ohi = __shfl_down(hi, off, 64);
        unsigned int olo = __shfl_down(lo, off, 64);
        unsigned long long ok = ((unsigned long long)ohi << 32) | olo;
        key = (ok < key) ? ok : key;
    }
    if (lane == 0) keys[w] = key;
    __syncthreads();
    if (tid < 2) {                                  // tid: point blockIdx*2+tid
        unsigned long long k0 = keys[2 * tid];
        unsigned long long k1 = keys[2 * tid + 1];
        unsigned long long km = (k1 < k0) ? k1 : k0;
        int pp = blockIdx.x * 2 + tid;
        out[1 + pp]           = __uint_as_float((unsigned int)(km >> 32));
        out[1 + P_TOTAL + pp] = (float)(unsigned int)(km & 0xFFFFFFFFu);
    }
}

// Deterministic single-block loss reduction: out[0] = sum(dist) * 1000/P.
// No atomics (R5 lesson).
__global__ __launch_bounds__(256) void msdf_loss(float* __restrict__ out)
{
    __shared__ float wsum[4];
    float s = 0.f;
    for (int k = 0; k < P_TOTAL / 256; ++k)
        s += out[1 + k * 256 + threadIdx.x];
    #pragma unroll
    for (int off = 32; off > 0; off >>= 1) s += __shfl_down(s, off, 64);
    int lane = threadIdx.x & 63, w = threadIdx.x >> 6;
    if (lane == 0) wsum[w] = s;
    __syncthreads();
    if (threadIdx.x == 0) {
        float tot = ((wsum[0] + wsum[1]) + wsum[2]) + wsum[3];
        out[0] = tot * (1000.0f / (float)P_TOTAL);
    }
}

extern "C" void kernel_launch(void* const* d_in, const int* in_sizes, int n_in,
                              void* d_out, int out_size, void* d_ws, size_t ws_size,
                              hipStream_t stream) {
    const float* verts  = (const float*)d_in[0];
    const int*   faces  = (const int*)d_in[1];
    const float* points = (const float*)d_in[2];
    float* out = (float*)d_out;
    float4* pre_n = (float4*)d_ws;                                      // 32 KB
    float4* pre_v = (float4*)((char*)d_ws + F_TOTAL * 16);              // 96 KB
    float4* pre_a = (float4*)((char*)d_ws + F_TOTAL * 16 * 4);          // 32 KB

    msdf_prep<<<dim3(F_TOTAL / 256), dim3(256), 0, stream>>>(verts, faces, pre_n, pre_v, pre_a);
    msdf_main<<<dim3(P_TOTAL / 2), dim3(TPB), 0, stream>>>(pre_n, pre_v, pre_a, points, out);
    msdf_loss<<<dim3(1), dim3(256), 0, stream>>>(out);
}